// Round 3
// baseline (108.026 us; speedup 1.0000x reference)
//
#include <hip/hip_runtime.h>
#include <hip/hip_bf16.h>
#include <stdint.h>

// Recommender: B=4096 users, L=200 history, D=64 emb, F=100000 films.
// Kernel 1: persistent 512-thread blocks pull users off an atomic queue.
// Per user: masked mean rating -> weights -> gather emb (8 lanes per dim,
// 32B segments), min/max/sum in registers, 16 bit-plane registers of the
// 16-bit sortable key (uniform trip count, unrolled 4 for load batching),
// bit-serial radix-select median via popcount+shuffles. L2-normalize ue(256),
// write x=[ue,fe] (B x 320) to workspace.
// Kernel 2: tiny MLP 320->128->64->1 + sigmoid, 4 users/block, f32 VALU.

#define B_ 4096
#define L_ 200
#define D_ 64

__global__ __launch_bounds__(512) void user_emb_kernel(
    const int* __restrict__ film_hist,
    const float* __restrict__ ratings,
    const int* __restrict__ lengths,
    const int* __restrict__ film_indices,
    const float* __restrict__ emb,
    float* __restrict__ x,
    int* __restrict__ ctr)
{
  __shared__ int   hist_s[L_];
  __shared__ float rat_s[L_];
  __shared__ float red[8];
  __shared__ float ue[4*D_];                 // [min|max|mean|med]
  __shared__ int   u_s;

  const int t = threadIdx.x;
  const int wave = t >> 6;
  const int lane = t & 63;
  const int sub  = lane >> 3;                // 0..7  (key subset)
  const int dloc = lane & 7;
  const int d    = wave * 8 + dloc;          // 0..63 (dim)

  for (;;) {
    if (t == 0) u_s = atomicAdd(ctr, 1);
    __syncthreads();
    const int b = u_s;
    if (b >= B_) return;                     // uniform exit

    const int n = lengths[b];

    // stage history + ratings; film embedding written straight to x
    float r = 0.f;
    if (t < n) {
      hist_s[t] = film_hist[(size_t)b*L_ + t];
      float rv = ratings[(size_t)b*L_ + t];
      rat_s[t] = rv; r = rv;
    }
    if (t >= 448) {
      int fi = film_indices[b];
      x[(size_t)b*320 + 256 + (t-448)] = emb[(size_t)fi*D_ + (t-448)];
    }

    // mean rating (block reduce; t>=n contribute 0)
    float s = r;
    #pragma unroll
    for (int off = 32; off; off >>= 1) s += __shfl_down(s, off);
    if (lane == 0) red[wave] = s;
    __syncthreads();
    const float mean_r = (red[0]+red[1]+red[2]+red[3]+red[4]+red[5]+red[6]+red[7]) / (float)n;

    // phase 1: gather + stats + bit-plane build, uniform trip count cmax.
    // lane (sub,dloc) handles keys l = sub, sub+8, ... for dim d.
    float vmin = __builtin_inff(), vmax = -__builtin_inff(), vsum = 0.f;
    uint32_t P[16];
    #pragma unroll
    for (int i = 0; i < 16; ++i) P[i] = 0u;

    const int cmax = (n + 7) >> 3;           // uniform across block
    const int c    = (n - sub + 7) >> 3;     // valid keys this lane (may be cmax-1)
    const float* embd = emb + d;
    #pragma unroll 4
    for (int i = 0; i < cmax; ++i) {
      const int l = sub + 8*i;
      const int lc = (l < n) ? l : (n-1);    // clamp: duplicate last valid key
      const int h = hist_s[lc];
      const float wgt = rat_s[lc] - mean_r + 0.1f;
      const float w = embd[(size_t)h * D_] * wgt;
      vmin = fminf(vmin, w); vmax = fmaxf(vmax, w);
      vsum += (l < n) ? w : 0.f;
      uint32_t u = __float_as_uint(w);
      uint32_t key = (u ^ (0x80000000u | (uint32_t)((int32_t)u >> 31))) >> 16; // sortable 16b
      #pragma unroll
      for (int bb = 0; bb < 16; ++bb) {
        uint32_t bitv = (key >> bb) & 1u;
        P[bb] = __builtin_amdgcn_alignbit(bitv, P[bb], 1);  // shift-in from top
      }
    }

    // combine min/max/sum across the 8 subs (lane bits 3,4,5)
    vmin = fminf(vmin, __shfl_xor(vmin, 8));
    vmin = fminf(vmin, __shfl_xor(vmin, 16));
    vmin = fminf(vmin, __shfl_xor(vmin, 32));
    vmax = fmaxf(vmax, __shfl_xor(vmax, 8));
    vmax = fmaxf(vmax, __shfl_xor(vmax, 16));
    vmax = fmaxf(vmax, __shfl_xor(vmax, 32));
    vsum += __shfl_xor(vsum, 8);
    vsum += __shfl_xor(vsum, 16);
    vsum += __shfl_xor(vsum, 32);

    // phase 2: bit-serial select of k-th smallest key, zero memory traffic.
    // keys sit in bits [32-cmax, 32-cmax+c-1] of each plane (shifted in from top).
    uint32_t alive = (c > 0) ? ((0xFFFFFFFFu << (32 - c)) >> (cmax - c)) : 0u;
    int k = (n - 1) >> 1;
    uint32_t prefix = 0;
    #pragma unroll
    for (int bb = 15; bb >= 0; --bb) {
      uint32_t z = alive & ~P[bb];
      int cnt = __popc(z);
      cnt += __shfl_xor(cnt, 8);
      cnt += __shfl_xor(cnt, 16);
      cnt += __shfl_xor(cnt, 32);
      const bool zero_side = (k < cnt);
      alive  = zero_side ? z : (alive & P[bb]);
      k      = zero_side ? k : (k - cnt);
      prefix = zero_side ? prefix : (prefix | (1u << bb));
    }

    if (sub == 0) {
      uint32_t key32 = (prefix << 16) | 0x8000u;  // bucket midpoint
      float med = (prefix & 0x8000u) ? __uint_as_float(key32 ^ 0x80000000u)
                                     : __uint_as_float(~key32);
      ue[d]      = vmin;
      ue[64 + d] = vmax;
      ue[128+ d] = vsum / (float)n;
      ue[192+ d] = med;
    }
    __syncthreads();

    // L2-normalize ue and write x[b, 0:256]
    float v = (t < 256) ? ue[t] : 0.f;
    float ss = v*v;
    #pragma unroll
    for (int off = 32; off; off >>= 1) ss += __shfl_down(ss, off);
    if (lane == 0) red[wave] = ss;
    __syncthreads();
    const float rn = 1.0f / sqrtf(red[0]+red[1]+red[2]+red[3]+red[4]+red[5]+red[6]+red[7]);
    if (t < 256) x[(size_t)b*320 + t] = v * rn;
    __syncthreads();                         // protect hist_s/u_s for next user
  }
}

#define U_ 4   // users per MLP block -> 1024 blocks

__global__ __launch_bounds__(256) void mlp_kernel(
    const float* __restrict__ x,
    const float* __restrict__ W1, const float* __restrict__ b1,
    const float* __restrict__ W2, const float* __restrict__ b2,
    const float* __restrict__ W3, const float* __restrict__ b3,
    float* __restrict__ out)
{
  __shared__ float xs[U_*320];
  __shared__ float h1s[U_*128];
  __shared__ float h2s[U_*64];
  const int t = threadIdx.x;
  const int u0 = blockIdx.x * U_;

  for (int i = t; i < U_*80; i += 256)
    ((float4*)xs)[i] = ((const float4*)(x + (size_t)u0*320))[i];
  __syncthreads();

  // h1 = relu(x @ W1 + b1): 4 users x 128 out; thread = (j, 2-user group)
  {
    const int j = t & 127, g = t >> 7;
    const int ub = g*2;
    float acc[2];
    const float bj = b1[j];
    acc[0] = bj; acc[1] = bj;
    for (int i = 0; i < 320; i += 4) {
      float w0 = W1[(i+0)*128 + j];
      float w1 = W1[(i+1)*128 + j];
      float w2 = W1[(i+2)*128 + j];
      float w3 = W1[(i+3)*128 + j];
      #pragma unroll
      for (int q = 0; q < 2; ++q) {
        float4 xv = *(const float4*)&xs[(ub+q)*320 + i];   // LDS broadcast in-wave
        acc[q] += xv.x*w0 + xv.y*w1 + xv.z*w2 + xv.w*w3;
      }
    }
    #pragma unroll
    for (int q = 0; q < 2; ++q) h1s[(ub+q)*128 + j] = fmaxf(acc[q], 0.f);
  }
  __syncthreads();

  // h2 = relu(h1 @ W2 + b2): 4 users x 64 out, 1 user per 64-thread group
  {
    const int j = t & 63, g = t >> 6;
    float acc = b2[j];
    for (int i = 0; i < 128; i += 4) {
      float w0 = W2[(i+0)*64 + j];
      float w1 = W2[(i+1)*64 + j];
      float w2 = W2[(i+2)*64 + j];
      float w3 = W2[(i+3)*64 + j];
      float4 hv = *(const float4*)&h1s[g*128 + i];
      acc += hv.x*w0 + hv.y*w1 + hv.z*w2 + hv.w*w3;
    }
    h2s[g*64 + j] = fmaxf(acc, 0.f);
  }
  __syncthreads();

  // out = sigmoid(h2 @ W3 + b3)
  if (t < U_*4) {
    const int u = t >> 2, sub = t & 3;
    float a = 0.f;
    #pragma unroll
    for (int i = 0; i < 16; ++i) a += h2s[u*64 + sub*16 + i] * W3[sub*16 + i];
    a += __shfl_xor(a, 1);
    a += __shfl_xor(a, 2);
    if (sub == 0) out[u0 + u] = 1.f / (1.f + __expf(-(a + b3[0])));
  }
}

extern "C" void kernel_launch(void* const* d_in, const int* in_sizes, int n_in,
                              void* d_out, int out_size, void* d_ws, size_t ws_size,
                              hipStream_t stream) {
  const int*   film_hist = (const int*)d_in[0];
  const float* ratings   = (const float*)d_in[1];
  const int*   lengths   = (const int*)d_in[2];
  const int*   film_idx  = (const int*)d_in[3];
  const float* emb       = (const float*)d_in[4];
  const float* W1 = (const float*)d_in[5];
  const float* b1 = (const float*)d_in[6];
  const float* W2 = (const float*)d_in[7];
  const float* b2 = (const float*)d_in[8];
  const float* W3 = (const float*)d_in[9];
  const float* b3 = (const float*)d_in[10];

  float* xbuf = (float*)d_ws;                      // B*320 f32 = 5,242,880 B
  const size_t xbytes = (size_t)B_*320*sizeof(float);
  // work-queue counter: tail of d_ws if it fits, else d_out (mlp overwrites all of d_out after)
  int* ctr = (ws_size >= xbytes + sizeof(int)) ? (int*)((char*)d_ws + xbytes)
                                               : (int*)d_out;
  hipMemsetAsync(ctr, 0, sizeof(int), stream);

  user_emb_kernel<<<1024, 512, 0, stream>>>(film_hist, ratings, lengths, film_idx, emb, xbuf, ctr);
  mlp_kernel<<<B_/U_, 256, 0, stream>>>(xbuf, W1, b1, W2, b2, W3, b3, (float*)d_out);
}

// Round 4
// 86.953 us; speedup vs baseline: 1.2423x; 1.2423x over previous
//
#include <hip/hip_runtime.h>
#include <hip/hip_bf16.h>
#include <stdint.h>

// Recommender: B=4096 users, L=200 history, D=64 emb, F=100000 films.
// Kernel 1 (one 512-thread block per user, static grid): masked mean rating ->
// weights -> gather emb (8 lanes per dim, 32B segments), software-pipelined
// in chunks of 4 with LDS-padded uniform trip count; min/max/sum in registers;
// 16 bit-plane registers of the 16-bit sortable key; bit-serial radix-select
// median via popcount+shuffles (zero memory traffic). L2-normalize ue(256),
// write x=[ue,fe] (B x 320) to workspace.
// Kernel 2: tiny MLP 320->128->64->1 + sigmoid, 8 users/block, f32 VALU.

#define B_ 4096
#define L_ 200
#define D_ 64
#define LPAD 224   // max 8*cmax4 = 8*ceil(ceil(200/8)/4)*4 = 224

__global__ __launch_bounds__(512, 8) void user_emb_kernel(
    const int* __restrict__ film_hist,
    const float* __restrict__ ratings,
    const int* __restrict__ lengths,
    const int* __restrict__ film_indices,
    const float* __restrict__ emb,
    float* __restrict__ x)
{
  __shared__ int   hist_s[LPAD];
  __shared__ float rat_s[LPAD];
  __shared__ float red[8];
  __shared__ float ue[4*D_];                 // [min|max|mean|med]

  const int b = blockIdx.x;
  const int t = threadIdx.x;
  const int wave = t >> 6;
  const int lane = t & 63;
  const int sub  = lane >> 3;                // 0..7  (key subset)
  const int dloc = lane & 7;
  const int d    = wave * 8 + dloc;          // 0..63 (dim)
  const int n = lengths[b];
  const int cmax  = (n + 7) >> 3;
  const int cmax4 = (cmax + 3) & ~3;         // uniform, multiple of 4, <=28

  // stage history + ratings; film embedding written straight to x
  float r = 0.f;
  if (t < n) {
    hist_s[t] = film_hist[(size_t)b*L_ + t];
    float rv = ratings[(size_t)b*L_ + t];
    rat_s[t] = rv; r = rv;
  }
  if (t >= 448) {
    int fi = film_indices[b];
    x[(size_t)b*320 + 256 + (t-448)] = emb[(size_t)fi*D_ + (t-448)];
  }

  // mean rating (block reduce; t>=n contribute 0)
  float s = r;
  #pragma unroll
  for (int off = 32; off; off >>= 1) s += __shfl_down(s, off);
  if (lane == 0) red[wave] = s;
  __syncthreads();
  const float mean_r = (red[0]+red[1]+red[2]+red[3]+red[4]+red[5]+red[6]+red[7]) / (float)n;
  const float mr1 = 0.1f - mean_r;

  // pad hist/rat up to 8*cmax4 with the last valid entry (visible post-barrier)
  for (int l = n + t; l < 8*cmax4; l += 512) {
    hist_s[l] = hist_s[n-1];
    rat_s[l]  = rat_s[n-1];
  }
  __syncthreads();

  // phase 1: gather + stats + bit-plane build; chunks of 4, prefetch 1 chunk.
  // lane (sub,dloc) handles keys l = sub, sub+8, ... for dim d.
  float vmin = __builtin_inff(), vmax = -__builtin_inff(), vsum = 0.f;
  uint32_t P[16];
  #pragma unroll
  for (int i = 0; i < 16; ++i) P[i] = 0u;

  const float* embd = emb + d;
  float vbuf[4], rbuf[4];
  {
    int hbuf[4];
    #pragma unroll
    for (int j = 0; j < 4; ++j) hbuf[j] = hist_s[sub + 8*j];
    #pragma unroll
    for (int j = 0; j < 4; ++j) rbuf[j] = rat_s[sub + 8*j];
    #pragma unroll
    for (int j = 0; j < 4; ++j) vbuf[j] = embd[(size_t)hbuf[j] * D_];
  }

  for (int i = 0; i < cmax4; i += 4) {
    float vn[4], rn[4];
    const bool more = (i + 4) < cmax4;
    if (more) {
      int hn[4];
      #pragma unroll
      for (int j = 0; j < 4; ++j) hn[j] = hist_s[sub + 8*(i+4+j)];
      #pragma unroll
      for (int j = 0; j < 4; ++j) rn[j] = rat_s[sub + 8*(i+4+j)];
      #pragma unroll
      for (int j = 0; j < 4; ++j) vn[j] = embd[(size_t)hn[j] * D_];
    }
    #pragma unroll
    for (int j = 0; j < 4; ++j) {
      const int l = sub + 8*(i+j);
      const float w = vbuf[j] * (rbuf[j] + mr1);
      vmin = fminf(vmin, w); vmax = fmaxf(vmax, w);
      vsum += (l < n) ? w : 0.f;
      uint32_t u = __float_as_uint(w);
      uint32_t key = (u ^ (0x80000000u | (uint32_t)((int32_t)u >> 31))) >> 16; // sortable 16b
      #pragma unroll
      for (int bb = 0; bb < 16; ++bb)
        P[bb] = __builtin_amdgcn_alignbit((key >> bb) & 1u, P[bb], 1); // shift-in from top
    }
    if (more) {
      #pragma unroll
      for (int j = 0; j < 4; ++j) { vbuf[j] = vn[j]; rbuf[j] = rn[j]; }
    }
  }

  // combine min/max/sum across the 8 subs (lane bits 3,4,5)
  vmin = fminf(vmin, __shfl_xor(vmin, 8));
  vmin = fminf(vmin, __shfl_xor(vmin, 16));
  vmin = fminf(vmin, __shfl_xor(vmin, 32));
  vmax = fmaxf(vmax, __shfl_xor(vmax, 8));
  vmax = fmaxf(vmax, __shfl_xor(vmax, 16));
  vmax = fmaxf(vmax, __shfl_xor(vmax, 32));
  vsum += __shfl_xor(vsum, 8);
  vsum += __shfl_xor(vsum, 16);
  vsum += __shfl_xor(vsum, 32);

  // phase 2: bit-serial select of k-th smallest key, zero memory traffic.
  // key i of this lane sits at bit (32-cmax4+i); valid i in [0,c).
  const int c = (n - sub + 7) >> 3;
  uint32_t alive = (c > 0) ? ((0xFFFFFFFFu << (32 - c)) >> (cmax4 - c)) : 0u;
  int k = (n - 1) >> 1;
  uint32_t prefix = 0;
  #pragma unroll
  for (int bb = 15; bb >= 0; --bb) {
    uint32_t z = alive & ~P[bb];
    int cnt = __popc(z);
    cnt += __shfl_xor(cnt, 8);
    cnt += __shfl_xor(cnt, 16);
    cnt += __shfl_xor(cnt, 32);
    const bool zero_side = (k < cnt);
    alive  = zero_side ? z : (alive & P[bb]);
    k      = zero_side ? k : (k - cnt);
    prefix = zero_side ? prefix : (prefix | (1u << bb));
  }

  if (sub == 0) {
    uint32_t key32 = (prefix << 16) | 0x8000u;  // bucket midpoint
    float med = (prefix & 0x8000u) ? __uint_as_float(key32 ^ 0x80000000u)
                                   : __uint_as_float(~key32);
    ue[d]      = vmin;
    ue[64 + d] = vmax;
    ue[128+ d] = vsum / (float)n;
    ue[192+ d] = med;
  }
  __syncthreads();

  // L2-normalize ue and write x[b, 0:256]
  float v = (t < 256) ? ue[t] : 0.f;
  float ss = v*v;
  #pragma unroll
  for (int off = 32; off; off >>= 1) ss += __shfl_down(ss, off);
  if (lane == 0) red[wave] = ss;
  __syncthreads();
  const float rn2 = 1.0f / sqrtf(red[0]+red[1]+red[2]+red[3]+red[4]+red[5]+red[6]+red[7]);
  if (t < 256) x[(size_t)b*320 + t] = v * rn2;
}

#define U_ 8   // users per MLP block -> 512 blocks

__global__ __launch_bounds__(256) void mlp_kernel(
    const float* __restrict__ x,
    const float* __restrict__ W1, const float* __restrict__ b1,
    const float* __restrict__ W2, const float* __restrict__ b2,
    const float* __restrict__ W3, const float* __restrict__ b3,
    float* __restrict__ out)
{
  __shared__ float xs[U_*320];
  __shared__ float h1s[U_*128];
  __shared__ float h2s[U_*64];
  const int t = threadIdx.x;
  const int u0 = blockIdx.x * U_;

  for (int i = t; i < U_*80; i += 256)
    ((float4*)xs)[i] = ((const float4*)(x + (size_t)u0*320))[i];
  __syncthreads();

  // h1 = relu(x @ W1 + b1): 8 users x 128 out; thread = (j, 4-user group)
  {
    const int j = t & 127, g = t >> 7;
    const int ub = g*4;
    float acc[4];
    const float bj = b1[j];
    #pragma unroll
    for (int q = 0; q < 4; ++q) acc[q] = bj;
    #pragma unroll 2
    for (int i = 0; i < 320; i += 4) {
      float w0 = W1[(i+0)*128 + j];
      float w1 = W1[(i+1)*128 + j];
      float w2 = W1[(i+2)*128 + j];
      float w3 = W1[(i+3)*128 + j];
      #pragma unroll
      for (int q = 0; q < 4; ++q) {
        float4 xv = *(const float4*)&xs[(ub+q)*320 + i];   // LDS broadcast in-wave
        acc[q] += xv.x*w0 + xv.y*w1 + xv.z*w2 + xv.w*w3;
      }
    }
    #pragma unroll
    for (int q = 0; q < 4; ++q) h1s[(ub+q)*128 + j] = fmaxf(acc[q], 0.f);
  }
  __syncthreads();

  // h2 = relu(h1 @ W2 + b2): 8 users x 64 out
  {
    const int j = t & 63, g = t >> 6;
    const int ub = g*2;
    float acc[2];
    const float bj = b2[j];
    acc[0] = bj; acc[1] = bj;
    #pragma unroll 2
    for (int i = 0; i < 128; i += 4) {
      float w0 = W2[(i+0)*64 + j];
      float w1 = W2[(i+1)*64 + j];
      float w2 = W2[(i+2)*64 + j];
      float w3 = W2[(i+3)*64 + j];
      #pragma unroll
      for (int q = 0; q < 2; ++q) {
        float4 hv = *(const float4*)&h1s[(ub+q)*128 + i];
        acc[q] += hv.x*w0 + hv.y*w1 + hv.z*w2 + hv.w*w3;
      }
    }
    #pragma unroll
    for (int q = 0; q < 2; ++q) h2s[(ub+q)*64 + j] = fmaxf(acc[q], 0.f);
  }
  __syncthreads();

  // out = sigmoid(h2 @ W3 + b3)
  if (t < U_*4) {
    const int u = t >> 2, sub = t & 3;
    float a = 0.f;
    #pragma unroll
    for (int i = 0; i < 16; ++i) a += h2s[u*64 + sub*16 + i] * W3[sub*16 + i];
    a += __shfl_xor(a, 1);
    a += __shfl_xor(a, 2);
    if (sub == 0) out[u0 + u] = 1.f / (1.f + __expf(-(a + b3[0])));
  }
}

extern "C" void kernel_launch(void* const* d_in, const int* in_sizes, int n_in,
                              void* d_out, int out_size, void* d_ws, size_t ws_size,
                              hipStream_t stream) {
  const int*   film_hist = (const int*)d_in[0];
  const float* ratings   = (const float*)d_in[1];
  const int*   lengths   = (const int*)d_in[2];
  const int*   film_idx  = (const int*)d_in[3];
  const float* emb       = (const float*)d_in[4];
  const float* W1 = (const float*)d_in[5];
  const float* b1 = (const float*)d_in[6];
  const float* W2 = (const float*)d_in[7];
  const float* b2 = (const float*)d_in[8];
  const float* W3 = (const float*)d_in[9];
  const float* b3 = (const float*)d_in[10];

  float* xbuf = (float*)d_ws;                 // B*320 f32 = 5.24 MB
  float* outp = (float*)d_out;

  user_emb_kernel<<<B_, 512, 0, stream>>>(film_hist, ratings, lengths, film_idx, emb, xbuf);
  mlp_kernel<<<B_/U_, 256, 0, stream>>>(xbuf, W1, b1, W2, b2, W3, b3, outp);
}

// Round 5
// 61.009 us; speedup vs baseline: 1.7707x; 1.4253x over previous
//
#include <hip/hip_runtime.h>
#include <hip/hip_bf16.h>
#include <stdint.h>

// Recommender: B=4096 users, L=200 history, D=64 emb, F=100000 films.
// Single fused kernel, one 512-thread block per user:
//  - masked mean rating -> weights -> gather emb (8 lanes per dim)
//  - min/max/sum in registers
//  - 16-bit sortable keys packed 2/word (16 words = 32 slots), then a dual
//    16x16 bit-matrix transpose (Hacker's Delight) yields the 16 bit-planes
//    in ~192 VALU instead of 32 VALU/key
//  - bit-serial radix-select median via popcount + 3 shfl_xor per bit
//  - L2-normalize ue(256) into LDS, append film emb -> x(320) in LDS
//  - fused MLP 320->128->64->1 + sigmoid (split-dot + LDS reduce), out[b].

#define B_ 4096
#define L_ 200
#define D_ 64
#define LPAD 224   // 8 * max cmax4 = 8*28

__global__ __launch_bounds__(512) void fused_kernel(
    const int* __restrict__ film_hist,
    const float* __restrict__ ratings,
    const int* __restrict__ lengths,
    const int* __restrict__ film_indices,
    const float* __restrict__ emb,
    const float* __restrict__ W1, const float* __restrict__ b1,
    const float* __restrict__ W2, const float* __restrict__ b2,
    const float* __restrict__ W3, const float* __restrict__ b3,
    float* __restrict__ out)
{
  __shared__ int   hist_s[LPAD];
  __shared__ float rat_s[LPAD];
  __shared__ float red[8];
  __shared__ float ue[4*D_];                 // [min|max|mean|med]
  __shared__ float xls[320];                 // [ue_norm(256) | fe(64)]
  __shared__ float ph[512];
  __shared__ float h1s[128];
  __shared__ float h2s[64];

  const int b = blockIdx.x;
  const int t = threadIdx.x;
  const int wave = t >> 6;
  const int lane = t & 63;
  const int sub  = lane >> 3;                // 0..7  (key subset)
  const int dloc = lane & 7;
  const int d    = wave * 8 + dloc;          // 0..63 (dim)
  const int n = lengths[b];
  const int cmax  = (n + 7) >> 3;            // <=25, block-uniform
  const int cmax4 = (cmax + 3) & ~3;         // multiple of 4, <=28

  // stage history + ratings; film embedding into xls[256..319]
  float r = 0.f;
  if (t < n) {
    hist_s[t] = film_hist[(size_t)b*L_ + t];
    float rv = ratings[(size_t)b*L_ + t];
    rat_s[t] = rv; r = rv;
  }
  if (t >= 448) {
    int fi = film_indices[b];
    xls[256 + (t-448)] = emb[(size_t)fi*D_ + (t-448)];
  }

  // mean rating (block reduce; t>=n contribute 0)
  float s = r;
  #pragma unroll
  for (int off = 32; off; off >>= 1) s += __shfl_down(s, off);
  if (lane == 0) red[wave] = s;
  __syncthreads();
  const float mean_r = (red[0]+red[1]+red[2]+red[3]+red[4]+red[5]+red[6]+red[7]) / (float)n;
  const float mr1 = 0.1f - mean_r;

  // pad hist/rat up to 8*cmax4 with the last valid entry
  for (int l = n + t; l < 8*cmax4; l += 512) {
    hist_s[l] = hist_s[n-1];
    rat_s[l]  = rat_s[n-1];
  }
  __syncthreads();

  // phase 1: gather + stats + key pack. lane (sub,dloc) owns keys l = sub+8i.
  float vmin = __builtin_inff(), vmax = -__builtin_inff(), vsum = 0.f;
  uint32_t W[16];
  #pragma unroll
  for (int i = 0; i < 16; ++i) W[i] = 0u;

  const float* embd = emb + d;
  float vb[2][4], rb[2][4];
  {
    #pragma unroll
    for (int j = 0; j < 4; ++j) {
      const int l = sub + 8*j;
      rb[0][j] = rat_s[l];
      vb[0][j] = embd[(size_t)hist_s[l] * D_];
    }
  }
  #pragma unroll
  for (int ch = 0; ch < 7; ++ch) {
    const int cur = ch & 1, nxt = cur ^ 1;
    if ((ch+1)*4 < cmax4) {                  // block-uniform branch
      #pragma unroll
      for (int j = 0; j < 4; ++j) {
        const int l = sub + 8*((ch+1)*4 + j);
        rb[nxt][j] = rat_s[l];
        vb[nxt][j] = embd[(size_t)hist_s[l] * D_];
      }
    }
    if (ch*4 < cmax4) {                      // block-uniform branch
      uint32_t kk[4];
      #pragma unroll
      for (int j = 0; j < 4; ++j) {
        const int l = sub + 8*(ch*4 + j);
        const float w = vb[cur][j] * (rb[cur][j] + mr1);
        vmin = fminf(vmin, w); vmax = fmaxf(vmax, w);
        vsum += (l < n) ? w : 0.f;
        uint32_t u = __float_as_uint(w);
        kk[j] = (u ^ (0x80000000u | (uint32_t)((int32_t)u >> 31))) >> 16;  // sortable 16b
      }
      W[2*ch]   = kk[0] | (kk[1] << 16);     // key idx 4ch+0 / +1
      W[2*ch+1] = kk[2] | (kk[3] << 16);     // key idx 4ch+2 / +3
    }
  }

  // combine min/max/sum across the 8 subs (lane bits 3,4,5)
  vmin = fminf(vmin, __shfl_xor(vmin, 8));
  vmin = fminf(vmin, __shfl_xor(vmin, 16));
  vmin = fminf(vmin, __shfl_xor(vmin, 32));
  vmax = fmaxf(vmax, __shfl_xor(vmax, 8));
  vmax = fmaxf(vmax, __shfl_xor(vmax, 16));
  vmax = fmaxf(vmax, __shfl_xor(vmax, 32));
  vsum += __shfl_xor(vsum, 8);
  vsum += __shfl_xor(vsum, 16);
  vsum += __shfl_xor(vsum, 32);

  // dual 16x16 bit-matrix transpose (both halves of each word in parallel).
  // Result: bit q of W[r] = old bit (15-r) of W[15-q] (per half) =>
  // plane for key-bit b is W[15-b]; key i sits at plane bit (15-(i>>1)) + 16*(i&1).
  #define XS(k, jj, m) { uint32_t tt = ((W[k] ^ (W[(k)|(jj)] >> (jj))) & (m)); \
                         W[k] ^= tt; W[(k)|(jj)] ^= (tt << (jj)); }
  XS(0,8,0x00FF00FFu) XS(1,8,0x00FF00FFu) XS(2,8,0x00FF00FFu) XS(3,8,0x00FF00FFu)
  XS(4,8,0x00FF00FFu) XS(5,8,0x00FF00FFu) XS(6,8,0x00FF00FFu) XS(7,8,0x00FF00FFu)
  XS(0,4,0x0F0F0F0Fu) XS(1,4,0x0F0F0F0Fu) XS(2,4,0x0F0F0F0Fu) XS(3,4,0x0F0F0F0Fu)
  XS(8,4,0x0F0F0F0Fu) XS(9,4,0x0F0F0F0Fu) XS(10,4,0x0F0F0F0Fu) XS(11,4,0x0F0F0F0Fu)
  XS(0,2,0x33333333u) XS(1,2,0x33333333u) XS(4,2,0x33333333u) XS(5,2,0x33333333u)
  XS(8,2,0x33333333u) XS(9,2,0x33333333u) XS(12,2,0x33333333u) XS(13,2,0x33333333u)
  XS(0,1,0x55555555u) XS(2,1,0x55555555u) XS(4,1,0x55555555u) XS(6,1,0x55555555u)
  XS(8,1,0x55555555u) XS(10,1,0x55555555u) XS(12,1,0x55555555u) XS(14,1,0x55555555u)
  #undef XS

  // phase 2: bit-serial select of k-th smallest key.
  // valid keys i in [0,c): even i -> low-half bits {15..16-ce}, odd -> {31..32-cf}
  const int c  = (n - sub + 7) >> 3;
  const int ce = (c + 1) >> 1, cf = c >> 1;
  uint32_t alive = ((1u << ce) - 1u) << (16 - ce);
  if (cf) alive |= ((1u << cf) - 1u) << (32 - cf);
  int k = (n - 1) >> 1;
  uint32_t prefix = 0;
  #pragma unroll
  for (int bb = 15; bb >= 0; --bb) {
    const uint32_t P = W[15 - bb];
    uint32_t z = alive & ~P;
    int cnt = __popc(z);
    cnt += __shfl_xor(cnt, 8);
    cnt += __shfl_xor(cnt, 16);
    cnt += __shfl_xor(cnt, 32);
    const bool zs = (k < cnt);
    alive  = zs ? z : (alive & P);
    k      = zs ? k : (k - cnt);
    prefix = zs ? prefix : (prefix | (1u << bb));
  }

  if (sub == 0) {
    uint32_t key32 = (prefix << 16) | 0x8000u;  // bucket midpoint
    float med = (prefix & 0x8000u) ? __uint_as_float(key32 ^ 0x80000000u)
                                   : __uint_as_float(~key32);
    ue[d]      = vmin;
    ue[64 + d] = vmax;
    ue[128+ d] = vsum / (float)n;
    ue[192+ d] = med;
  }
  __syncthreads();

  // L2-normalize ue into xls[0..255]
  float v = (t < 256) ? ue[t] : 0.f;
  float ss = v*v;
  #pragma unroll
  for (int off = 32; off; off >>= 1) ss += __shfl_down(ss, off);
  if (lane == 0) red[wave] = ss;
  __syncthreads();
  const float rn2 = 1.0f / sqrtf(red[0]+red[1]+red[2]+red[3]+red[4]+red[5]+red[6]+red[7]);
  if (t < 256) xls[t] = v * rn2;
  __syncthreads();

  // MLP h1 = relu(x @ W1 + b1): 128 outs, 4-way split dot
  {
    const int j = t & 127, q = t >> 7;
    const float* Wp = W1 + (size_t)(q*80)*128 + j;
    const float* xp = xls + q*80;
    float a0 = 0.f, a1 = 0.f;
    #pragma unroll 8
    for (int i = 0; i < 80; i += 2) {
      a0 += xp[i]   * Wp[(size_t)i*128];
      a1 += xp[i+1] * Wp[(size_t)(i+1)*128];
    }
    ph[t] = a0 + a1;
  }
  __syncthreads();
  if (t < 128) h1s[t] = fmaxf(b1[t] + ph[t] + ph[t+128] + ph[t+256] + ph[t+384], 0.f);
  __syncthreads();

  // MLP h2 = relu(h1 @ W2 + b2): 64 outs, 8-way split dot
  {
    const int j = t & 63, q = t >> 6;
    const float* Wp = W2 + (size_t)(q*16)*64 + j;
    const float* hp = h1s + q*16;
    float a = 0.f;
    #pragma unroll
    for (int i = 0; i < 16; ++i) a += hp[i] * Wp[(size_t)i*64];
    ph[t] = a;
  }
  __syncthreads();
  if (t < 64) {
    float h = b2[t] + ph[t] + ph[t+64] + ph[t+128] + ph[t+192]
                    + ph[t+256] + ph[t+320] + ph[t+384] + ph[t+448];
    h2s[t] = fmaxf(h, 0.f);
  }
  __syncthreads();

  // out = sigmoid(h2 @ W3 + b3): wave 0 reduces 64 terms
  if (t < 64) {
    float vv = h2s[t] * W3[t];
    #pragma unroll
    for (int off = 32; off; off >>= 1) vv += __shfl_down(vv, off);
    if (t == 0) out[b] = 1.f / (1.f + __expf(-(vv + b3[0])));
  }
}

extern "C" void kernel_launch(void* const* d_in, const int* in_sizes, int n_in,
                              void* d_out, int out_size, void* d_ws, size_t ws_size,
                              hipStream_t stream) {
  const int*   film_hist = (const int*)d_in[0];
  const float* ratings   = (const float*)d_in[1];
  const int*   lengths   = (const int*)d_in[2];
  const int*   film_idx  = (const int*)d_in[3];
  const float* emb       = (const float*)d_in[4];
  const float* W1 = (const float*)d_in[5];
  const float* b1 = (const float*)d_in[6];
  const float* W2 = (const float*)d_in[7];
  const float* b2 = (const float*)d_in[8];
  const float* W3 = (const float*)d_in[9];
  const float* b3 = (const float*)d_in[10];

  fused_kernel<<<B_, 512, 0, stream>>>(film_hist, ratings, lengths, film_idx, emb,
                                       W1, b1, W2, b2, W3, b3, (float*)d_out);
}